// Round 11
// baseline (378.990 us; speedup 1.0000x reference)
//
#include <hip/hip_runtime.h>
#include <hip/hip_bf16.h>

#define Dq 1024
#define Hq 4096
#define Tq 4096
#define MAXTILES 40

// ws layout (bytes)
#define XB_OFF 65536
#define HC_OFF (XB_OFF + Tq * Dq * 2)
#define WT_OFF (HC_OFF + MAXTILES * 128 * Hq * 2)

// meta layout (ints)
#define M_NT 0
#define M_CNT 8
#define M_POFF 16
#define M_CUR 32
#define M_TE 64
#define M_TR 128
#define M_EXP 512
#define M_PERM 4608

typedef __attribute__((ext_vector_type(8))) short bf16x8;
typedef __attribute__((ext_vector_type(4))) float f32x4;

__device__ __forceinline__ short f2bf(float f) {
    __hip_bfloat16 h = __float2bfloat16(f);
    return *reinterpret_cast<short*>(&h);
}

__device__ __forceinline__ float gelu_tanh(float x) {
    float u = 0.7978845608028654f * (x + 0.044715f * x * x * x);
    return x / (1.0f + __expf(-2.0f * u));
}

typedef __attribute__((address_space(1))) const void gvoid;
typedef __attribute__((address_space(3))) void lvoid;
__device__ __forceinline__ void glds16(const void* g, void* l) {
    __builtin_amdgcn_global_load_lds((gvoid*)g, (lvoid*)l, 16, 0, 0);
}

#define WAITVM_(N) asm volatile("s_waitcnt vmcnt(" #N ")" ::: "memory")
#define WAITVM(N) WAITVM_(N)

__global__ void k_init(int* meta) {
    int i = blockIdx.x * 256 + threadIdx.x;
    if (i < M_PERM + MAXTILES * 128) meta[i] = 0;
}

// per-expert transpose: in [E][R][C] fp32 -> out [E][C][R] bf16.  64x64 tiles.
__global__ void k_tr(const float* __restrict__ in, short* __restrict__ out, int R, int C) {
    __shared__ float t[64][65];
    int e = blockIdx.z;
    int c0 = blockIdx.x * 64;
    int r0 = blockIdx.y * 64;
    const float* ine = in + (size_t)e * R * C;
    short* oute = out + (size_t)e * R * C;
    int tt = threadIdx.x;
    int lr = tt >> 4;
    int lc = (tt & 15) * 4;
#pragma unroll
    for (int p = 0; p < 4; ++p) {
        int r = p * 16 + lr;
        float4 v = *(const float4*)(ine + (size_t)(r0 + r) * C + c0 + lc);
        t[r][lc] = v.x; t[r][lc + 1] = v.y; t[r][lc + 2] = v.z; t[r][lc + 3] = v.w;
    }
    __syncthreads();
#pragma unroll
    for (int p = 0; p < 4; ++p) {
        int c = p * 16 + lr;
        short4 s;
        s.x = f2bf(t[lc][c]); s.y = f2bf(t[lc + 1][c]);
        s.z = f2bf(t[lc + 2][c]); s.w = f2bf(t[lc + 3][c]);
        *(short4*)(oute + (size_t)(c0 + c) * R + r0 + lc) = s;
    }
}

// route + fold x->bf16 conversion
__global__ void k_route(const float* __restrict__ x, const float* __restrict__ Wg,
                        const float* __restrict__ bg, int* meta, short* __restrict__ xb) {
    int wave = threadIdx.x >> 6;
    int lane = threadIdx.x & 63;
    int t = blockIdx.x * 4 + wave;
    const float* xr = x + (size_t)t * Dq;
    float acc[8];
#pragma unroll
    for (int e = 0; e < 8; ++e) acc[e] = 0.0f;
#pragma unroll
    for (int j = 0; j < 16; ++j) {
        int d = j * 64 + lane;
        float xv = xr[d];
        xb[(size_t)t * Dq + d] = f2bf(xv);
        float4 w0 = *(const float4*)(Wg + (size_t)d * 8);
        float4 w1 = *(const float4*)(Wg + (size_t)d * 8 + 4);
        acc[0] += xv * w0.x; acc[1] += xv * w0.y; acc[2] += xv * w0.z; acc[3] += xv * w0.w;
        acc[4] += xv * w1.x; acc[5] += xv * w1.y; acc[6] += xv * w1.z; acc[7] += xv * w1.w;
    }
#pragma unroll
    for (int e = 0; e < 8; ++e) {
#pragma unroll
        for (int off = 32; off > 0; off >>= 1) acc[e] += __shfl_xor(acc[e], off);
    }
    if (lane == 0) {
        float best = acc[0] + bg[0];
        int be = 0;
#pragma unroll
        for (int e = 1; e < 8; ++e) {
            float v = acc[e] + bg[e];
            if (v > best) { best = v; be = e; }
        }
        meta[M_EXP + t] = be;
        atomicAdd(&meta[M_CNT + be], 1);
    }
}

__global__ void k_scan(int* meta) {
    if (threadIdx.x != 0) return;
    int off = 0, nt = 0;
    for (int e = 0; e < 8; ++e) {
        meta[M_POFF + e] = off;
        int c = meta[M_CNT + e];
        int m = (c + 127) / 128;
        for (int j = 0; j < m; ++j) {
            meta[M_TE + nt] = e;
            meta[M_TR + nt] = off + j * 128;
            ++nt;
        }
        off += m * 128;
    }
    meta[M_POFF + 8] = off;
    meta[M_NT] = nt;
}

__global__ void k_scatter(int* meta) {
    int t = blockIdx.x * 256 + threadIdx.x;
    if (t >= Tq) return;
    int e = meta[M_EXP + t];
    int pos = atomicAdd(&meta[M_CUR + e], 1);
    meta[M_PERM + meta[M_POFF + e] + pos] = t;
}

// ---- wave-private barrier-free GEMM: block = 4 waves, each wave owns a
// 64x64 output tile and PRIVATE LDS dbuf (A 64x32 + B 64x32 bf16 per buf).
// LDS: As[2][4][64][32], Bs same = 64 KB/block -> 2 blocks/CU.
// Swizzle: lds chunk q holds global chunk q^((row>>1)&3) (involution, <=2-way).
#define GEMM_SETUP()                                                           \
    int tt = threadIdx.x, w = tt >> 6, lane = tt & 63;                         \
    int fr = lane & 15, fg = lane >> 4;                                        \
    int r16 = lane >> 2;                                                       \
    int csw = ((lane & 3) ^ ((lane >> 3) & 3)) * 8;                            \
    int ldsW = w * 2048;                                                       \
    int wm = (w >> 1) * 64, wn = (w & 1) * 64;                                 \
    int aoff[4], boff[4];                                                      \
    _Pragma("unroll")                                                          \
    for (int f = 0; f < 4; ++f) {                                              \
        int row = f * 16 + fr;                                                 \
        int sw = (fg ^ ((row >> 1) & 3)) * 8;                                  \
        aoff[f] = ldsW + row * 32 + sw;                                        \
        boff[f] = ldsW + row * 32 + sw;                                        \
    }                                                                          \
    f32x4 acc[4][4];                                                           \
    _Pragma("unroll")                                                          \
    for (int a = 0; a < 4; ++a)                                                \
      _Pragma("unroll")                                                        \
      for (int b = 0; b < 4; ++b) acc[a][b] = (f32x4){0.f, 0.f, 0.f, 0.f};

// barrier-free K-loop, BK=32, prefetch distance 1, vmcnt counts own 8 glds.
#define KLOOP(NS)                                                              \
  _Pragma("unroll 2")                                                          \
  for (int t = 0; t < (NS); ++t) {                                             \
    const int P = t & 1;                                                       \
    if (t + 1 < (NS)) {                                                        \
      _Pragma("unroll")                                                        \
      for (int s = 0; s < 4; ++s)                                              \
        glds16(aSrc[s] + (size_t)(t + 1) * 32,                                 \
               As + (1 - P) * 8192 + ldsW + s * 512);                          \
      _Pragma("unroll")                                                        \
      for (int s = 0; s < 4; ++s)                                              \
        glds16(bSrc[s] + (size_t)(t + 1) * 32,                                 \
               Bs + (1 - P) * 8192 + ldsW + s * 512);                          \
      WAITVM(8);                                                               \
    } else {                                                                   \
      WAITVM(0);                                                               \
    }                                                                          \
    bf16x8 af[4], bv[4];                                                       \
    _Pragma("unroll")                                                          \
    for (int f = 0; f < 4; ++f) {                                              \
      af[f] = *(const bf16x8*)(&As[P * 8192 + aoff[f]]);                       \
      bv[f] = *(const bf16x8*)(&Bs[P * 8192 + boff[f]]);                       \
    }                                                                          \
    asm volatile("s_waitcnt lgkmcnt(0)" ::: "memory");                         \
    __builtin_amdgcn_sched_barrier(0);                                         \
    _Pragma("unroll")                                                          \
    for (int fm = 0; fm < 4; ++fm)                                             \
      _Pragma("unroll")                                                        \
      for (int fn = 0; fn < 4; ++fn)                                           \
        acc[fm][fn] = __builtin_amdgcn_mfma_f32_16x16x32_bf16(                 \
            af[fm], bv[fn], acc[fm][fn], 0, 0, 0);                             \
  }

// ---------------- GEMM1: Hc[i,h] = gelu(sum_d xb[perm[i],d] * W1T[e,h,d]) ----------------
__global__ __launch_bounds__(256, 2) void k_gemm1(const short* __restrict__ xb,
                                                  const short* __restrict__ W1T,
                                                  const int* __restrict__ meta,
                                                  short* __restrict__ Hc) {
    __shared__ short As[2 * 8192];
    __shared__ short Bs[2 * 8192];
    // 1280 blocks: xcd owns 4 H-panels x 40 mt (mt fast -> B panel set L2-hot)
    int hw = blockIdx.x;
    int xcd = hw & 7, q = hw >> 3;          // q 0..159
    int mt = q % 40;
    int n0 = (xcd * 4 + q / 40) * 128;      // 32 panels
    if (mt >= meta[M_NT]) return;
    int e = meta[M_TE + mt];
    int i0 = meta[M_TR + mt];
    const int* perm = meta + M_PERM;

    GEMM_SETUP()

    const short* aSrc[4];
    const short* bSrc[4];
#pragma unroll
    for (int s = 0; s < 4; ++s) {
        int arow = wm + s * 16 + r16;
        aSrc[s] = xb + (size_t)perm[i0 + arow] * Dq + csw;
        int brow = wn + s * 16 + r16;
        bSrc[s] = W1T + ((size_t)e * Hq + n0 + brow) * Dq + csw;
    }

    // prologue: tile 0 -> buf0 (wave-private)
#pragma unroll
    for (int s = 0; s < 4; ++s) {
        glds16(aSrc[s], As + ldsW + s * 512);
        glds16(bSrc[s], Bs + ldsW + s * 512);
    }

    KLOOP(32)

    // epilogue: gelu -> bf16 Hc (padded rows hold dup data; never combined)
#pragma unroll
    for (int fm = 0; fm < 4; ++fm) {
        int rbase = i0 + wm + fm * 16 + fg * 4;
#pragma unroll
        for (int fn = 0; fn < 4; ++fn) {
            int col = n0 + wn + fn * 16 + fr;
#pragma unroll
            for (int p = 0; p < 4; ++p) {
                float v = gelu_tanh(acc[fm][fn][p]);
                Hc[(size_t)(rbase + p) * Hq + col] = f2bf(v);
            }
        }
    }
}

// ---------------- GEMM2: out[perm[i],d] += sum_h Hc[i,h] * W2T[e,d,h]  (split-K=2) ----------------
__global__ __launch_bounds__(256, 2) void k_gemm2(const short* __restrict__ Hc,
                                                  const short* __restrict__ W2T,
                                                  const int* __restrict__ meta,
                                                  float* __restrict__ out) {
    __shared__ short As[2 * 8192];
    __shared__ short Bs[2 * 8192];
    // 640 blocks: xcd owns 1 D-panel x 40 mt x 2 sk
    int hw = blockIdx.x;
    int xcd = hw & 7, q = hw >> 3;          // q 0..79
    int mt = q % 40;
    int sk = q / 40;
    int n0 = xcd * 128;
    int kbase = sk * (Hq / 2);
    if (mt >= meta[M_NT]) return;
    int e = meta[M_TE + mt];
    int i0 = meta[M_TR + mt];
    const int* perm = meta + M_PERM;
    int vend = meta[M_POFF + e] + meta[M_CNT + e];

    GEMM_SETUP()

    const short* aSrc[4];
    const short* bSrc[4];
#pragma unroll
    for (int s = 0; s < 4; ++s) {
        int arow = wm + s * 16 + r16;
        aSrc[s] = Hc + (size_t)(i0 + arow) * Hq + kbase + csw;
        int brow = wn + s * 16 + r16;
        bSrc[s] = W2T + ((size_t)e * Dq + n0 + brow) * Hq + kbase + csw;
    }

#pragma unroll
    for (int s = 0; s < 4; ++s) {
        glds16(aSrc[s], As + ldsW + s * 512);
        glds16(bSrc[s], Bs + ldsW + s * 512);
    }

    KLOOP(64)

    // epilogue: atomic accumulate valid rows (exactly 2 addends/elem)
#pragma unroll
    for (int fm = 0; fm < 4; ++fm) {
        int rbase = i0 + wm + fm * 16 + fg * 4;
#pragma unroll
        for (int p = 0; p < 4; ++p) {
            int i = rbase + p;
            if (i < vend) {
                int tok = perm[i];
#pragma unroll
                for (int fn = 0; fn < 4; ++fn) {
                    int col = n0 + wn + fn * 16 + fr;
                    atomicAdd(&out[(size_t)tok * Dq + col], acc[fm][fn][p]);
                }
            }
        }
    }
}

extern "C" void kernel_launch(void* const* d_in, const int* in_sizes, int n_in,
                              void* d_out, int out_size, void* d_ws, size_t ws_size,
                              hipStream_t stream) {
    const float* x  = (const float*)d_in[0];
    const float* W1 = (const float*)d_in[1];
    const float* W2 = (const float*)d_in[2];
    const float* Wg = (const float*)d_in[3];
    const float* bg = (const float*)d_in[4];
    float* out = (float*)d_out;
    int* meta = (int*)d_ws;
    short* xb = (short*)((char*)d_ws + XB_OFF);
    short* Hc = (short*)((char*)d_ws + HC_OFF);
    short* WT = (short*)((char*)d_ws + WT_OFF);

    k_init<<<38, 256, 0, stream>>>(meta);
    hipMemsetAsync(d_out, 0, (size_t)Tq * Dq * 4, stream);
    k_route<<<Tq / 4, 256, 0, stream>>>(x, Wg, bg, meta, xb);
    k_scan<<<1, 64, 0, stream>>>(meta);
    k_scatter<<<Tq / 256, 256, 0, stream>>>(meta);
    // W1 [E][Dq][Hq] -> WT [E][Hq][Dq] bf16
    k_tr<<<dim3(Hq / 64, Dq / 64, 8), 256, 0, stream>>>(W1, WT, Dq, Hq);
    k_gemm1<<<1280, 256, 0, stream>>>(xb, WT, meta, Hc);
    // W2 [E][Hq][Dq] -> WT [E][Dq][Hq] bf16 (reuses buffer)
    k_tr<<<dim3(Dq / 64, Hq / 64, 8), 256, 0, stream>>>(W2, WT, Hq, Dq);
    k_gemm2<<<640, 256, 0, stream>>>(Hc, WT, meta, out);
}

// Round 12
// 305.189 us; speedup vs baseline: 1.2418x; 1.2418x over previous
//
#include <hip/hip_runtime.h>
#include <hip/hip_bf16.h>

#define Dq 1024
#define Hq 4096
#define Tq 4096
#define MAXTILES 40

// ws layout (bytes)
#define XB_OFF 65536
#define HC_OFF (XB_OFF + Tq * Dq * 2)

// meta layout (ints)
#define M_NT 0
#define M_CNT 8
#define M_POFF 16
#define M_CUR 32
#define M_TE 64
#define M_TR 128
#define M_EXP 512
#define M_PERM 4608

typedef __attribute__((ext_vector_type(8))) short bf16x8;
typedef __attribute__((ext_vector_type(8))) short short8;
typedef __attribute__((ext_vector_type(4))) float f32x4;

__device__ __forceinline__ short f2bf(float f) {
    __hip_bfloat16 h = __float2bfloat16(f);
    return *reinterpret_cast<short*>(&h);
}

__device__ __forceinline__ float gelu_tanh(float x) {
    float u = 0.7978845608028654f * (x + 0.044715f * x * x * x);
    return x / (1.0f + __expf(-2.0f * u));
}

typedef __attribute__((address_space(1))) const void gvoid;
typedef __attribute__((address_space(3))) void lvoid;
__device__ __forceinline__ void glds16(const void* g, void* l) {
    __builtin_amdgcn_global_load_lds((gvoid*)g, (lvoid*)l, 16, 0, 0);
}

#define WAITVM_(N) asm volatile("s_waitcnt vmcnt(" #N ")" ::: "memory")
#define WAITVM(N) WAITVM_(N)

__global__ void k_init(int* meta) {
    int i = blockIdx.x * 256 + threadIdx.x;
    if (i < M_PERM + MAXTILES * 128) meta[i] = 0;
}

// route + fold x->bf16 conversion
__global__ void k_route(const float* __restrict__ x, const float* __restrict__ Wg,
                        const float* __restrict__ bg, int* meta, short* __restrict__ xb) {
    int wave = threadIdx.x >> 6;
    int lane = threadIdx.x & 63;
    int t = blockIdx.x * 4 + wave;
    const float* xr = x + (size_t)t * Dq;
    float acc[8];
#pragma unroll
    for (int e = 0; e < 8; ++e) acc[e] = 0.0f;
#pragma unroll
    for (int j = 0; j < 16; ++j) {
        int d = j * 64 + lane;
        float xv = xr[d];
        xb[(size_t)t * Dq + d] = f2bf(xv);
        float4 w0 = *(const float4*)(Wg + (size_t)d * 8);
        float4 w1 = *(const float4*)(Wg + (size_t)d * 8 + 4);
        acc[0] += xv * w0.x; acc[1] += xv * w0.y; acc[2] += xv * w0.z; acc[3] += xv * w0.w;
        acc[4] += xv * w1.x; acc[5] += xv * w1.y; acc[6] += xv * w1.z; acc[7] += xv * w1.w;
    }
#pragma unroll
    for (int e = 0; e < 8; ++e) {
#pragma unroll
        for (int off = 32; off > 0; off >>= 1) acc[e] += __shfl_xor(acc[e], off);
    }
    if (lane == 0) {
        float best = acc[0] + bg[0];
        int be = 0;
#pragma unroll
        for (int e = 1; e < 8; ++e) {
            float v = acc[e] + bg[e];
            if (v > best) { best = v; be = e; }
        }
        meta[M_EXP + t] = be;
        atomicAdd(&meta[M_CNT + be], 1);
    }
}

__global__ void k_scan(int* meta) {
    if (threadIdx.x != 0) return;
    int off = 0, nt = 0;
    for (int e = 0; e < 8; ++e) {
        meta[M_POFF + e] = off;
        int c = meta[M_CNT + e];
        int m = (c + 127) / 128;
        for (int j = 0; j < m; ++j) {
            meta[M_TE + nt] = e;
            meta[M_TR + nt] = off + j * 128;
            ++nt;
        }
        off += m * 128;
    }
    meta[M_POFF + 8] = off;
    meta[M_NT] = nt;
}

__global__ void k_scatter(int* meta) {
    int t = blockIdx.x * 256 + threadIdx.x;
    if (t >= Tq) return;
    int e = meta[M_EXP + t];
    int pos = atomicAdd(&meta[M_CUR + e], 1);
    meta[M_PERM + meta[M_POFF + e] + pos] = t;
}

// ---- 128x128xBK32 tile, 256 thr / 4 waves, wave tile 64x64.
// A: bf16, glds16 dist-1, LDS linear [128][32] swizzled-source, 8KB/buf.
// B: fp32 natural [K][N], reg dist-2 (8 x dword2), cvt->ds_write [n][40], 10KB/buf.
#define GEMM_SETUP()                                                           \
    int tt = threadIdx.x, w = tt >> 6, lane = tt & 63;                         \
    int fr = lane & 15, fg = lane >> 4;                                        \
    int csw = ((lane & 3) ^ ((lane >> 2) & 3)) * 8;                            \
    int ldsA0 = w * 512 + lane * 8;        /* slot s adds s*2048 shorts */     \
    int bn2 = (tt & 63) * 2;               /* B col pair */                    \
    int br0 = (tt >> 6) * 8;               /* B row group (k) */               \
    int bwr0 = bn2 * 40 + br0;             /* B write (shorts), +40 for col+1*/\
    int wm = (w >> 1) * 64, wn = (w & 1) * 64;                                 \
    int aoff[4], boff[4];                                                      \
    _Pragma("unroll")                                                          \
    for (int f = 0; f < 4; ++f) {                                              \
        int m = wm + f * 16 + fr;                                              \
        aoff[f] = m * 32 + ((fg ^ (m & 3)) * 8);                               \
        int n = wn + f * 16 + fr;                                              \
        boff[f] = n * 40 + fg * 8;                                             \
    }                                                                          \
    f32x4 acc[4][4];                                                           \
    _Pragma("unroll")                                                          \
    for (int a = 0; a < 4; ++a)                                                \
      _Pragma("unroll")                                                        \
      for (int b = 0; b < 4; ++b) acc[a][b] = (f32x4){0.f, 0.f, 0.f, 0.f};

// issue B reg-loads for tile T into register set BR (8 x float2)
#define BLOAD(BR, T)                                                           \
  {                                                                            \
    _Pragma("unroll")                                                          \
    for (int i = 0; i < 8; ++i)                                                \
      BR[i] = *(const float2*)(bSrc + ((size_t)(T) * 32 + br0 + i) * ldb);     \
  }

// cvt BR -> bf16, write 2 x b128 into B buffer BUF
#define BWRITE(BR, BUF)                                                        \
  {                                                                            \
    _Pragma("unroll")                                                          \
    for (int j = 0; j < 2; ++j) {                                              \
      short8 v;                                                                \
      _Pragma("unroll")                                                        \
      for (int i = 0; i < 8; ++i) v[i] = f2bf(j ? BR[i].y : BR[i].x);          \
      *(short8*)(&Bs[(BUF) * 5120 + bwr0 + j * 40]) = v;                       \
    }                                                                          \
  }

// one K-step. BRC = regs holding B(t+1) (consumed), BRN = set loaded with B(t+2).
#define KSTEP(T, NS, BRC, BRN)                                                 \
  {                                                                            \
    const int P = (T) & 1;                                                     \
    if ((T) + 1 < (NS)) {                                                      \
      glds16(aSrc0 + ((T) + 1) * 32, As + (1 - P) * 4096 + ldsA0);             \
      glds16(aSrc1 + ((T) + 1) * 32, As + (1 - P) * 4096 + 2048 + ldsA0);      \
    }                                                                          \
    if ((T) + 2 < (NS)) BLOAD(BRN, (T) + 2)                                    \
    if ((T) + 2 < (NS)) { WAITVM(18); }                                        \
    else if ((T) + 1 < (NS)) { WAITVM(10); }                                   \
    else { WAITVM(0); }                                                        \
    __builtin_amdgcn_s_barrier();                                              \
    asm volatile("" ::: "memory");                                             \
    bf16x8 af[4], bv[4];                                                       \
    _Pragma("unroll")                                                          \
    for (int f = 0; f < 4; ++f) {                                              \
      af[f] = *(const bf16x8*)(&As[P * 4096 + aoff[f]]);                       \
      bv[f] = *(const bf16x8*)(&Bs[P * 5120 + boff[f]]);                       \
    }                                                                          \
    if ((T) + 2 < (NS)) { WAITVM(10); }                                        \
    else if ((T) + 1 < (NS)) { WAITVM(2); }                                    \
    if ((T) + 1 < (NS)) BWRITE(BRC, 1 - P)                                     \
    asm volatile("s_waitcnt lgkmcnt(0)" ::: "memory");                         \
    __builtin_amdgcn_sched_barrier(0);                                         \
    __builtin_amdgcn_s_setprio(1);                                             \
    _Pragma("unroll")                                                          \
    for (int fm = 0; fm < 4; ++fm)                                             \
      _Pragma("unroll")                                                        \
      for (int fn = 0; fn < 4; ++fn)                                           \
        acc[fm][fn] = __builtin_amdgcn_mfma_f32_16x16x32_bf16(                 \
            af[fm], bv[fn], acc[fm][fn], 0, 0, 0);                             \
    __builtin_amdgcn_s_setprio(0);                                             \
    __builtin_amdgcn_s_barrier();                                              \
    asm volatile("" ::: "memory");                                             \
  }

// prologue: B(0)->BR0, A(0) glds, B(1)->BR1; vmcnt(10) => B(0) ready; write buf0.
#define GPROLOGUE()                                                            \
  {                                                                            \
    BLOAD(brE, 0)                                                              \
    glds16(aSrc0, As + ldsA0);                                                 \
    glds16(aSrc1, As + 2048 + ldsA0);                                          \
    BLOAD(brO, 1)                                                              \
    WAITVM(10);                                                                \
    BWRITE(brE, 0)                                                             \
  }

#define GLOOP(NS)                                                              \
  float2 brE[8], brO[8];                                                       \
  GPROLOGUE()                                                                  \
  _Pragma("unroll 2")                                                          \
  for (int t = 0; t < (NS); ++t) {                                             \
    if ((t & 1) == 0) KSTEP(t, NS, brO, brE)                                   \
    else              KSTEP(t, NS, brE, brO)                                   \
  }

// ---------------- GEMM1: Hc[i,h] = gelu(sum_d xb[perm[i],d] * W1[e,d,h]) ----------------
__global__ __launch_bounds__(256, 3) void k_gemm1(const short* __restrict__ xb,
                                                  const float* __restrict__ W1,
                                                  const int* __restrict__ meta,
                                                  short* __restrict__ Hc) {
    __shared__ short As[2 * 4096];   // 16 KB
    __shared__ short Bs[2 * 5120];   // 20 KB
    // 1280 blocks: xcd owns 4 H-panels x 40 mt (mt fast)
    int hw = blockIdx.x;
    int xcd = hw & 7, q = hw >> 3;
    int mt = q % 40;
    int n0 = (xcd * 4 + q / 40) * 128;
    if (mt >= meta[M_NT]) return;
    int e = meta[M_TE + mt];
    int i0 = meta[M_TR + mt];
    const int* perm = meta + M_PERM;

    GEMM_SETUP()

    int arow0 = w * 16 + (lane >> 2);
    const short* aSrc0 = xb + (size_t)perm[i0 + arow0] * Dq + csw;
    const short* aSrc1 = xb + (size_t)perm[i0 + 64 + arow0] * Dq + csw;
    const float* bSrc = W1 + (size_t)e * Dq * Hq + n0 + bn2;
    const int ldb = Hq;

    GLOOP(32)

    // epilogue: gelu -> bf16 Hc (padded rows hold dup data; never combined)
#pragma unroll
    for (int fm = 0; fm < 4; ++fm) {
        int rbase = i0 + wm + fm * 16 + fg * 4;
#pragma unroll
        for (int fn = 0; fn < 4; ++fn) {
            int col = n0 + wn + fn * 16 + fr;
#pragma unroll
            for (int p = 0; p < 4; ++p) {
                float v = gelu_tanh(acc[fm][fn][p]);
                Hc[(size_t)(rbase + p) * Hq + col] = f2bf(v);
            }
        }
    }
}

// ---------------- GEMM2: out[perm[i],d] += sum_h Hc[i,h] * W2[e,h,d]  (split-K=2) ----------------
__global__ __launch_bounds__(256, 3) void k_gemm2(const short* __restrict__ Hc,
                                                  const float* __restrict__ W2,
                                                  const int* __restrict__ meta,
                                                  float* __restrict__ out) {
    __shared__ short As[2 * 4096];
    __shared__ short Bs[2 * 5120];
    // 640 blocks: xcd owns 1 D-panel x 40 mt x 2 sk
    int hw = blockIdx.x;
    int xcd = hw & 7, q = hw >> 3;
    int mt = q % 40;
    int sk = q / 40;
    int n0 = xcd * 128;
    int kbase = sk * (Hq / 2);
    if (mt >= meta[M_NT]) return;
    int e = meta[M_TE + mt];
    int i0 = meta[M_TR + mt];
    const int* perm = meta + M_PERM;
    int vend = meta[M_POFF + e] + meta[M_CNT + e];

    GEMM_SETUP()

    int arow0 = w * 16 + (lane >> 2);
    const short* aSrc0 = Hc + (size_t)(i0 + arow0) * Hq + kbase + csw;
    const short* aSrc1 = Hc + (size_t)(i0 + 64 + arow0) * Hq + kbase + csw;
    const float* bSrc = W2 + ((size_t)e * Hq + kbase) * Dq + n0 + bn2;
    const int ldb = Dq;

    GLOOP(64)

    // epilogue: atomic accumulate valid rows (exactly 2 addends/elem)
#pragma unroll
    for (int fm = 0; fm < 4; ++fm) {
        int rbase = i0 + wm + fm * 16 + fg * 4;
#pragma unroll
        for (int p = 0; p < 4; ++p) {
            int i = rbase + p;
            if (i < vend) {
                int tok = perm[i];
#pragma unroll
                for (int fn = 0; fn < 4; ++fn) {
                    int col = n0 + wn + fn * 16 + fr;
                    atomicAdd(&out[(size_t)tok * Dq + col], acc[fm][fn][p]);
                }
            }
        }
    }
}

extern "C" void kernel_launch(void* const* d_in, const int* in_sizes, int n_in,
                              void* d_out, int out_size, void* d_ws, size_t ws_size,
                              hipStream_t stream) {
    const float* x  = (const float*)d_in[0];
    const float* W1 = (const float*)d_in[1];
    const float* W2 = (const float*)d_in[2];
    const float* Wg = (const float*)d_in[3];
    const float* bg = (const float*)d_in[4];
    float* out = (float*)d_out;
    int* meta = (int*)d_ws;
    short* xb = (short*)((char*)d_ws + XB_OFF);
    short* Hc = (short*)((char*)d_ws + HC_OFF);

    k_init<<<38, 256, 0, stream>>>(meta);
    hipMemsetAsync(d_out, 0, (size_t)Tq * Dq * 4, stream);
    k_route<<<Tq / 4, 256, 0, stream>>>(x, Wg, bg, meta, xb);
    k_scan<<<1, 64, 0, stream>>>(meta);
    k_scatter<<<Tq / 256, 256, 0, stream>>>(meta);
    k_gemm1<<<1280, 256, 0, stream>>>(xb, W1, meta, Hc);
    k_gemm2<<<640, 256, 0, stream>>>(Hc, W2, meta, out);
}

// Round 13
// 304.742 us; speedup vs baseline: 1.2436x; 1.0015x over previous
//
#include <hip/hip_runtime.h>
#include <hip/hip_bf16.h>

#define Dq 1024
#define Hq 4096
#define Tq 4096
#define MAXTILES 40

// ws layout (bytes)
#define XB_OFF 65536
#define HC_OFF (XB_OFF + Tq * Dq * 2)

// meta layout (ints)
#define M_NT 0
#define M_CNT 8
#define M_POFF 16
#define M_CUR 32
#define M_TE 64
#define M_TR 128
#define M_EXP 512
#define M_PERM 4608

typedef __attribute__((ext_vector_type(8))) short bf16x8;
typedef __attribute__((ext_vector_type(8))) short short8;
typedef __attribute__((ext_vector_type(4))) float f32x4;

__device__ __forceinline__ short f2bf(float f) {
    __hip_bfloat16 h = __float2bfloat16(f);
    return *reinterpret_cast<short*>(&h);
}

__device__ __forceinline__ float gelu_tanh(float x) {
    float u = 0.7978845608028654f * (x + 0.044715f * x * x * x);
    return x / (1.0f + __expf(-2.0f * u));
}

typedef __attribute__((address_space(1))) const void gvoid;
typedef __attribute__((address_space(3))) void lvoid;
__device__ __forceinline__ void glds16(const void* g, void* l) {
    __builtin_amdgcn_global_load_lds((gvoid*)g, (lvoid*)l, 16, 0, 0);
}

#define WAITVM_(N) asm volatile("s_waitcnt vmcnt(" #N ")" ::: "memory")
#define WAITVM(N) WAITVM_(N)

__global__ void k_init(int* meta) {
    int i = blockIdx.x * 256 + threadIdx.x;
    if (i < M_PERM + MAXTILES * 128) meta[i] = 0;
}

// route + fold x->bf16 conversion
__global__ void k_route(const float* __restrict__ x, const float* __restrict__ Wg,
                        const float* __restrict__ bg, int* meta, short* __restrict__ xb) {
    int wave = threadIdx.x >> 6;
    int lane = threadIdx.x & 63;
    int t = blockIdx.x * 4 + wave;
    const float* xr = x + (size_t)t * Dq;
    float acc[8];
#pragma unroll
    for (int e = 0; e < 8; ++e) acc[e] = 0.0f;
#pragma unroll
    for (int j = 0; j < 16; ++j) {
        int d = j * 64 + lane;
        float xv = xr[d];
        xb[(size_t)t * Dq + d] = f2bf(xv);
        float4 w0 = *(const float4*)(Wg + (size_t)d * 8);
        float4 w1 = *(const float4*)(Wg + (size_t)d * 8 + 4);
        acc[0] += xv * w0.x; acc[1] += xv * w0.y; acc[2] += xv * w0.z; acc[3] += xv * w0.w;
        acc[4] += xv * w1.x; acc[5] += xv * w1.y; acc[6] += xv * w1.z; acc[7] += xv * w1.w;
    }
#pragma unroll
    for (int e = 0; e < 8; ++e) {
#pragma unroll
        for (int off = 32; off > 0; off >>= 1) acc[e] += __shfl_xor(acc[e], off);
    }
    if (lane == 0) {
        float best = acc[0] + bg[0];
        int be = 0;
#pragma unroll
        for (int e = 1; e < 8; ++e) {
            float v = acc[e] + bg[e];
            if (v > best) { best = v; be = e; }
        }
        meta[M_EXP + t] = be;
        atomicAdd(&meta[M_CNT + be], 1);
    }
}

__global__ void k_scan(int* meta) {
    if (threadIdx.x != 0) return;
    int off = 0, nt = 0;
    for (int e = 0; e < 8; ++e) {
        meta[M_POFF + e] = off;
        int c = meta[M_CNT + e];
        int m = (c + 127) / 128;
        for (int j = 0; j < m; ++j) {
            meta[M_TE + nt] = e;
            meta[M_TR + nt] = off + j * 128;
            ++nt;
        }
        off += m * 128;
    }
    meta[M_POFF + 8] = off;
    meta[M_NT] = nt;
}

__global__ void k_scatter(int* meta) {
    int t = blockIdx.x * 256 + threadIdx.x;
    if (t >= Tq) return;
    int e = meta[M_EXP + t];
    int pos = atomicAdd(&meta[M_CUR + e], 1);
    meta[M_PERM + meta[M_POFF + e] + pos] = t;
}

// ---- 128x128xBK32 tile, 256 thr / 4 waves, wave tile 64x64.
// A: bf16, glds16 dist-1, LDS linear [128][32] swizzled-source, 8KB/buf.
// B: fp32 natural [K][N], reg dist-2 (8 x dword2), cvt->ds_write [n][40], 10KB/buf.
#define GEMM_SETUP()                                                           \
    int tt = threadIdx.x, w = tt >> 6, lane = tt & 63;                         \
    int fr = lane & 15, fg = lane >> 4;                                        \
    int csw = ((lane & 3) ^ ((lane >> 2) & 3)) * 8;                            \
    int ldsA0 = w * 512 + lane * 8;        /* slot s adds s*2048 shorts */     \
    int bn2 = (tt & 63) * 2;               /* B col pair */                    \
    int br0 = (tt >> 6) * 8;               /* B row group (k) */               \
    int bwr0 = bn2 * 40 + br0;             /* B write (shorts), +40 for col+1*/\
    int wm = (w >> 1) * 64, wn = (w & 1) * 64;                                 \
    int aoff[4], boff[4];                                                      \
    _Pragma("unroll")                                                          \
    for (int f = 0; f < 4; ++f) {                                              \
        int m = wm + f * 16 + fr;                                              \
        aoff[f] = m * 32 + ((fg ^ (m & 3)) * 8);                               \
        int n = wn + f * 16 + fr;                                              \
        boff[f] = n * 40 + fg * 8;                                             \
    }                                                                          \
    f32x4 acc[4][4];                                                           \
    _Pragma("unroll")                                                          \
    for (int a = 0; a < 4; ++a)                                                \
      _Pragma("unroll")                                                        \
      for (int b = 0; b < 4; ++b) acc[a][b] = (f32x4){0.f, 0.f, 0.f, 0.f};

// issue B reg-loads for tile T into register set BR (8 x float2)
#define BLOAD(BR, T)                                                           \
  {                                                                            \
    _Pragma("unroll")                                                          \
    for (int i = 0; i < 8; ++i)                                                \
      BR[i] = *(const float2*)(bSrc + ((size_t)(T) * 32 + br0 + i) * ldb);     \
  }

// cvt BR -> bf16, write 2 x b128 into B buffer BUF
#define BWRITE(BR, BUF)                                                        \
  {                                                                            \
    _Pragma("unroll")                                                          \
    for (int j = 0; j < 2; ++j) {                                              \
      short8 v;                                                                \
      _Pragma("unroll")                                                        \
      for (int i = 0; i < 8; ++i) v[i] = f2bf(j ? BR[i].y : BR[i].x);          \
      *(short8*)(&Bs[(BUF) * 5120 + bwr0 + j * 40]) = v;                       \
    }                                                                          \
  }

// one K-step. BRC = regs holding B(t+1) (consumed), BRN = set loaded with B(t+2).
#define KSTEP(T, NS, BRC, BRN)                                                 \
  {                                                                            \
    const int P = (T) & 1;                                                     \
    if ((T) + 1 < (NS)) {                                                      \
      glds16(aSrc0 + ((T) + 1) * 32, As + (1 - P) * 4096 + ldsA0);             \
      glds16(aSrc1 + ((T) + 1) * 32, As + (1 - P) * 4096 + 2048 + ldsA0);      \
    }                                                                          \
    if ((T) + 2 < (NS)) BLOAD(BRN, (T) + 2)                                    \
    if ((T) + 2 < (NS)) { WAITVM(18); }                                        \
    else if ((T) + 1 < (NS)) { WAITVM(10); }                                   \
    else { WAITVM(0); }                                                        \
    __builtin_amdgcn_s_barrier();                                              \
    asm volatile("" ::: "memory");                                             \
    bf16x8 af[4], bv[4];                                                       \
    _Pragma("unroll")                                                          \
    for (int f = 0; f < 4; ++f) {                                              \
      af[f] = *(const bf16x8*)(&As[P * 4096 + aoff[f]]);                       \
      bv[f] = *(const bf16x8*)(&Bs[P * 5120 + boff[f]]);                       \
    }                                                                          \
    if ((T) + 2 < (NS)) { WAITVM(10); }                                        \
    else if ((T) + 1 < (NS)) { WAITVM(2); }                                    \
    if ((T) + 1 < (NS)) BWRITE(BRC, 1 - P)                                     \
    asm volatile("s_waitcnt lgkmcnt(0)" ::: "memory");                         \
    __builtin_amdgcn_sched_barrier(0);                                         \
    __builtin_amdgcn_s_setprio(1);                                             \
    _Pragma("unroll")                                                          \
    for (int fm = 0; fm < 4; ++fm)                                             \
      _Pragma("unroll")                                                        \
      for (int fn = 0; fn < 4; ++fn)                                           \
        acc[fm][fn] = __builtin_amdgcn_mfma_f32_16x16x32_bf16(                 \
            af[fm], bv[fn], acc[fm][fn], 0, 0, 0);                             \
    __builtin_amdgcn_s_setprio(0);                                             \
    __builtin_amdgcn_s_barrier();                                              \
    asm volatile("" ::: "memory");                                             \
  }

// prologue: B(0)->BR0, A(0) glds, B(1)->BR1; vmcnt(10) => B(0) ready; write buf0.
#define GPROLOGUE()                                                            \
  {                                                                            \
    BLOAD(brE, 0)                                                              \
    glds16(aSrc0, As + ldsA0);                                                 \
    glds16(aSrc1, As + 2048 + ldsA0);                                          \
    BLOAD(brO, 1)                                                              \
    WAITVM(10);                                                                \
    BWRITE(brE, 0)                                                             \
  }

#define GLOOP(NS)                                                              \
  float2 brE[8], brO[8];                                                       \
  GPROLOGUE()                                                                  \
  _Pragma("unroll 2")                                                          \
  for (int t = 0; t < (NS); ++t) {                                             \
    if ((t & 1) == 0) KSTEP(t, NS, brO, brE)                                   \
    else              KSTEP(t, NS, brE, brO)                                   \
  }

// ---------------- GEMM1: Hc[i,h] = gelu(sum_d xb[perm[i],d] * W1[e,d,h]) ----------------
__global__ __launch_bounds__(256, 3) void k_gemm1(const short* __restrict__ xb,
                                                  const float* __restrict__ W1,
                                                  const int* __restrict__ meta,
                                                  short* __restrict__ Hc) {
    __shared__ short As[2 * 4096];   // 16 KB
    __shared__ short Bs[2 * 5120];   // 20 KB
    // 1280 blocks: xcd owns 4 H-panels x 40 mt (mt fast)
    int hw = blockIdx.x;
    int xcd = hw & 7, q = hw >> 3;
    int mt = q % 40;
    int n0 = (xcd * 4 + q / 40) * 128;
    if (mt >= meta[M_NT]) return;
    int e = meta[M_TE + mt];
    int i0 = meta[M_TR + mt];
    const int* perm = meta + M_PERM;

    GEMM_SETUP()

    int arow0 = w * 16 + (lane >> 2);
    const short* aSrc0 = xb + (size_t)perm[i0 + arow0] * Dq + csw;
    const short* aSrc1 = xb + (size_t)perm[i0 + 64 + arow0] * Dq + csw;
    const float* bSrc = W1 + (size_t)e * Dq * Hq + n0 + bn2;
    const int ldb = Hq;

    GLOOP(32)

    // epilogue: gelu -> bf16 Hc (padded rows hold dup data; never combined)
#pragma unroll
    for (int fm = 0; fm < 4; ++fm) {
        int rbase = i0 + wm + fm * 16 + fg * 4;
#pragma unroll
        for (int fn = 0; fn < 4; ++fn) {
            int col = n0 + wn + fn * 16 + fr;
#pragma unroll
            for (int p = 0; p < 4; ++p) {
                float v = gelu_tanh(acc[fm][fn][p]);
                Hc[(size_t)(rbase + p) * Hq + col] = f2bf(v);
            }
        }
    }
}

// ---------------- GEMM2: out[perm[i],d] += sum_h Hc[i,h] * W2[e,h,d]  (split-K=2) ----------------
__global__ __launch_bounds__(256, 3) void k_gemm2(const short* __restrict__ Hc,
                                                  const float* __restrict__ W2,
                                                  const int* __restrict__ meta,
                                                  float* __restrict__ out) {
    __shared__ short As[2 * 4096];
    __shared__ short Bs[2 * 5120];
    // 640 blocks: xcd owns 1 D-panel x 40 mt x 2 sk
    int hw = blockIdx.x;
    int xcd = hw & 7, q = hw >> 3;
    int mt = q % 40;
    int sk = q / 40;
    int n0 = xcd * 128;
    int kbase = sk * (Hq / 2);
    if (mt >= meta[M_NT]) return;
    int e = meta[M_TE + mt];
    int i0 = meta[M_TR + mt];
    const int* perm = meta + M_PERM;
    int vend = meta[M_POFF + e] + meta[M_CNT + e];

    GEMM_SETUP()

    int arow0 = w * 16 + (lane >> 2);
    const short* aSrc0 = Hc + (size_t)(i0 + arow0) * Hq + kbase + csw;
    const short* aSrc1 = Hc + (size_t)(i0 + 64 + arow0) * Hq + kbase + csw;
    const float* bSrc = W2 + ((size_t)e * Hq + kbase) * Dq + n0 + bn2;
    const int ldb = Dq;

    GLOOP(64)

    // epilogue: atomic accumulate valid rows (exactly 2 addends/elem)
#pragma unroll
    for (int fm = 0; fm < 4; ++fm) {
        int rbase = i0 + wm + fm * 16 + fg * 4;
#pragma unroll
        for (int p = 0; p < 4; ++p) {
            int i = rbase + p;
            if (i < vend) {
                int tok = perm[i];
#pragma unroll
                for (int fn = 0; fn < 4; ++fn) {
                    int col = n0 + wn + fn * 16 + fr;
                    atomicAdd(&out[(size_t)tok * Dq + col], acc[fm][fn][p]);
                }
            }
        }
    }
}

extern "C" void kernel_launch(void* const* d_in, const int* in_sizes, int n_in,
                              void* d_out, int out_size, void* d_ws, size_t ws_size,
                              hipStream_t stream) {
    const float* x  = (const float*)d_in[0];
    const float* W1 = (const float*)d_in[1];
    const float* W2 = (const float*)d_in[2];
    const float* Wg = (const float*)d_in[3];
    const float* bg = (const float*)d_in[4];
    float* out = (float*)d_out;
    int* meta = (int*)d_ws;
    short* xb = (short*)((char*)d_ws + XB_OFF);
    short* Hc = (short*)((char*)d_ws + HC_OFF);

    k_init<<<38, 256, 0, stream>>>(meta);
    hipMemsetAsync(d_out, 0, (size_t)Tq * Dq * 4, stream);
    k_route<<<Tq / 4, 256, 0, stream>>>(x, Wg, bg, meta, xb);
    k_scan<<<1, 64, 0, stream>>>(meta);
    k_scatter<<<Tq / 256, 256, 0, stream>>>(meta);
    k_gemm1<<<1280, 256, 0, stream>>>(xb, W1, meta, Hc);
    k_gemm2<<<640, 256, 0, stream>>>(Hc, W2, meta, out);
}

// Round 14
// 285.747 us; speedup vs baseline: 1.3263x; 1.0665x over previous
//
#include <hip/hip_runtime.h>
#include <hip/hip_bf16.h>

#define Dq 1024
#define Hq 4096
#define Tq 4096
#define MAXTILES 40

// ws layout (bytes)
#define XB_OFF 65536
#define HC_OFF (XB_OFF + Tq * Dq * 2)

// meta layout (ints)
#define M_NT 0
#define M_CNT 8
#define M_POFF 16
#define M_CUR 32
#define M_TE 64
#define M_TR 128
#define M_EXP 512
#define M_PERM 4608

typedef __attribute__((ext_vector_type(8))) short bf16x8;
typedef __attribute__((ext_vector_type(4))) float f32x4;

__device__ __forceinline__ short f2bf(float f) {
    __hip_bfloat16 h = __float2bfloat16(f);
    return *reinterpret_cast<short*>(&h);
}

__device__ __forceinline__ float gelu_tanh(float x) {
    float u = 0.7978845608028654f * (x + 0.044715f * x * x * x);
    return x / (1.0f + __expf(-2.0f * u));
}

typedef __attribute__((address_space(1))) const void gvoid;
typedef __attribute__((address_space(3))) void lvoid;
__device__ __forceinline__ void glds16(const void* g, void* l) {
    __builtin_amdgcn_global_load_lds((gvoid*)g, (lvoid*)l, 16, 0, 0);
}

#define WAITVM_(N) asm volatile("s_waitcnt vmcnt(" #N ")" ::: "memory")
#define WAITVM(N) WAITVM_(N)

__global__ void k_init(int* meta) {
    int i = blockIdx.x * 256 + threadIdx.x;
    if (i < M_PERM + MAXTILES * 128) meta[i] = 0;
}

// route + fold x->bf16 conversion
__global__ void k_route(const float* __restrict__ x, const float* __restrict__ Wg,
                        const float* __restrict__ bg, int* meta, short* __restrict__ xb) {
    int wave = threadIdx.x >> 6;
    int lane = threadIdx.x & 63;
    int t = blockIdx.x * 4 + wave;
    const float* xr = x + (size_t)t * Dq;
    float acc[8];
#pragma unroll
    for (int e = 0; e < 8; ++e) acc[e] = 0.0f;
#pragma unroll
    for (int j = 0; j < 16; ++j) {
        int d = j * 64 + lane;
        float xv = xr[d];
        xb[(size_t)t * Dq + d] = f2bf(xv);
        float4 w0 = *(const float4*)(Wg + (size_t)d * 8);
        float4 w1 = *(const float4*)(Wg + (size_t)d * 8 + 4);
        acc[0] += xv * w0.x; acc[1] += xv * w0.y; acc[2] += xv * w0.z; acc[3] += xv * w0.w;
        acc[4] += xv * w1.x; acc[5] += xv * w1.y; acc[6] += xv * w1.z; acc[7] += xv * w1.w;
    }
#pragma unroll
    for (int e = 0; e < 8; ++e) {
#pragma unroll
        for (int off = 32; off > 0; off >>= 1) acc[e] += __shfl_xor(acc[e], off);
    }
    if (lane == 0) {
        float best = acc[0] + bg[0];
        int be = 0;
#pragma unroll
        for (int e = 1; e < 8; ++e) {
            float v = acc[e] + bg[e];
            if (v > best) { best = v; be = e; }
        }
        meta[M_EXP + t] = be;
        atomicAdd(&meta[M_CNT + be], 1);
    }
}

__global__ void k_scan(int* meta) {
    if (threadIdx.x != 0) return;
    int off = 0, nt = 0;
    for (int e = 0; e < 8; ++e) {
        meta[M_POFF + e] = off;
        int c = meta[M_CNT + e];
        int m = (c + 127) / 128;
        for (int j = 0; j < m; ++j) {
            meta[M_TE + nt] = e;
            meta[M_TR + nt] = off + j * 128;
            ++nt;
        }
        off += m * 128;
    }
    meta[M_POFF + 8] = off;
    meta[M_NT] = nt;
}

__global__ void k_scatter(int* meta) {
    int t = blockIdx.x * 256 + threadIdx.x;
    if (t >= Tq) return;
    int e = meta[M_EXP + t];
    int pos = atomicAdd(&meta[M_CUR + e], 1);
    meta[M_PERM + meta[M_POFF + e] + pos] = t;
}

// One K-step (BK=64). Issue next tile's loads, wait counted vmcnt, cvt+write B,
// barrier, fragment reads + 32 MFMA, barrier.  Provably race-free 2-buffer ledger.
#define STEP(RC, RN, P, ISS, KN, LDB)                                          \
  {                                                                            \
    if (ISS) {                                                                 \
      _Pragma("unroll")                                                        \
      for (int s = 0; s < 4; ++s)                                              \
        glds16(aSrc[s] + (size_t)(KN) * 64, As + (1 - (P)) * 8192 + ldsA[s]);  \
      _Pragma("unroll")                                                        \
      for (int r = 0; r < 8; ++r)                                              \
        RN[r] = *(const float4*)(bSrc + ((size_t)(KN) * 64 + r) * (LDB));      \
      WAITVM(12);                                                              \
    } else {                                                                   \
      WAITVM(0);                                                               \
    }                                                                          \
    _Pragma("unroll")                                                          \
    for (int j = 0; j < 4; ++j) {                                              \
      bf16x8 v;                                                                \
      _Pragma("unroll")                                                        \
      for (int r = 0; r < 8; ++r) v[r] = f2bf(((const float*)&RC[r])[j]);      \
      *(bf16x8*)(Bs + (P) * 8192 + bwoff[j]) = v;                              \
    }                                                                          \
    asm volatile("s_waitcnt lgkmcnt(0)" ::: "memory");                         \
    __builtin_amdgcn_s_barrier();                                              \
    asm volatile("" ::: "memory");                                             \
    __builtin_amdgcn_sched_barrier(0);                                         \
    _Pragma("unroll")                                                          \
    for (int s2 = 0; s2 < 2; ++s2) {                                           \
      bf16x8 af[4], bfv[4];                                                    \
      _Pragma("unroll")                                                        \
      for (int f = 0; f < 4; ++f) {                                            \
        af[f]  = *(const bf16x8*)(&As[(P) * 8192 + aoff[s2][f]]);              \
        bfv[f] = *(const bf16x8*)(&Bs[(P) * 8192 + boff[s2][f]]);              \
      }                                                                        \
      __builtin_amdgcn_s_setprio(1);                                           \
      _Pragma("unroll")                                                        \
      for (int fm = 0; fm < 4; ++fm)                                           \
        _Pragma("unroll")                                                      \
        for (int fn = 0; fn < 4; ++fn)                                         \
          acc[fm][fn] = __builtin_amdgcn_mfma_f32_16x16x32_bf16(               \
              af[fm], bfv[fn], acc[fm][fn], 0, 0, 0);                          \
      __builtin_amdgcn_s_setprio(0);                                           \
    }                                                                          \
    __builtin_amdgcn_s_barrier();                                              \
    asm volatile("" ::: "memory");                                             \
  }

// shared per-thread setup for the 128x128xBK64 tile (4 waves, 64x64 wave tile)
#define GEMM_SETUP()                                                           \
    int tt = threadIdx.x, w = tt >> 6, lane = tt & 63;                         \
    int fr = lane & 15, fg = lane >> 4;                                        \
    int rlo = lane >> 3, csw = (lane & 7) ^ rlo;                               \
    int ldsA[4];                                                               \
    _Pragma("unroll")                                                          \
    for (int s = 0; s < 4; ++s) ldsA[s] = (s * 32 + w * 8) * 64;               \
    int n4 = (tt & 31) * 4, kb = (tt >> 5) * 8;                                \
    int bwoff[4];                                                              \
    _Pragma("unroll")                                                          \
    for (int j = 0; j < 4; ++j) {                                              \
      int n = n4 + j;                                                          \
      bwoff[j] = n * 64 + (((kb >> 3) ^ ((n + (n >> 3)) & 7)) * 8);            \
    }                                                                          \
    int wm = (w >> 1) * 64, wn = (w & 1) * 64;                                 \
    int aoff[2][4], boff[2][4];                                                \
    _Pragma("unroll")                                                          \
    for (int s2 = 0; s2 < 2; ++s2)                                             \
      _Pragma("unroll")                                                        \
      for (int f = 0; f < 4; ++f) {                                            \
        int c = s2 * 4 + fg;                                                   \
        int m = wm + f * 16 + fr;                                              \
        aoff[s2][f] = m * 64 + ((c ^ (m & 7)) * 8);                            \
        int n = wn + f * 16 + fr;                                              \
        boff[s2][f] = n * 64 + ((c ^ ((n + (n >> 3)) & 7)) * 8);               \
      }                                                                        \
    f32x4 acc[4][4];                                                           \
    _Pragma("unroll")                                                          \
    for (int a = 0; a < 4; ++a)                                                \
      _Pragma("unroll")                                                        \
      for (int b = 0; b < 4; ++b) acc[a][b] = (f32x4){0.f, 0.f, 0.f, 0.f};

// ---------------- GEMM1: Hc[i,h] = gelu(sum_d xb[perm[i],d] * W1[e,d,h]) ----------------
__global__ __launch_bounds__(256, 2) void k_gemm1(const short* __restrict__ xb,
                                                  const float* __restrict__ W1,
                                                  const int* __restrict__ meta,
                                                  short* __restrict__ Hc) {
    __shared__ short As[2 * 128 * 64];
    __shared__ short Bs[2 * 128 * 64];
    // XCD grouping: 1280 blocks; per XCD 160 = 40 mt (slow) x 4 panels (fast)
    int hw = blockIdx.x;
    int swzid = (hw & 7) * 160 + (hw >> 3);
    int q = swzid % 160;
    int mt = q >> 2;
    int n0 = ((swzid / 160) * 4 + (q & 3)) * 128;
    if (mt >= meta[M_NT]) return;
    int e = meta[M_TE + mt];
    int i0 = meta[M_TR + mt];
    const int* perm = meta + M_PERM;

    GEMM_SETUP()

    const short* aSrc[4];
#pragma unroll
    for (int s = 0; s < 4; ++s) {
        int row = s * 32 + w * 8 + rlo;
        aSrc[s] = xb + (size_t)perm[i0 + row] * Dq + csw * 8;
    }
    const float* bSrc = W1 + ((size_t)e * Dq + kb) * Hq + n0 + n4;

    float4 rB0[8], rB1[8];
    // prologue: tile 0
#pragma unroll
    for (int s = 0; s < 4; ++s) glds16(aSrc[s], As + ldsA[s]);
#pragma unroll
    for (int r = 0; r < 8; ++r) rB0[r] = *(const float4*)(bSrc + (size_t)r * Hq);

    for (int t = 0; t < 16; t += 2) {
        STEP(rB0, rB1, 0, true, t + 1, Hq)
        STEP(rB1, rB0, 1, (t + 2) < 16, t + 2, Hq)
    }

    // epilogue: gelu -> bf16 Hc (padded rows hold dup data; never combined)
#pragma unroll
    for (int fm = 0; fm < 4; ++fm) {
        int rbase = i0 + wm + fm * 16 + fg * 4;
#pragma unroll
        for (int fn = 0; fn < 4; ++fn) {
            int col = n0 + wn + fn * 16 + fr;
#pragma unroll
            for (int p = 0; p < 4; ++p) {
                float v = gelu_tanh(acc[fm][fn][p]);
                Hc[(size_t)(rbase + p) * Hq + col] = f2bf(v);
            }
        }
    }
}

// ---------------- GEMM2: out[perm[i],d] += sum_h Hc[i,h] * W2[e,h,d]  (split-K=2) ----------------
__global__ __launch_bounds__(256, 2) void k_gemm2(const short* __restrict__ Hc,
                                                  const float* __restrict__ W2,
                                                  const int* __restrict__ meta,
                                                  float* __restrict__ out) {
    __shared__ short As[2 * 128 * 64];
    __shared__ short Bs[2 * 128 * 64];
    // 640 blocks; per XCD 80 = 1 panel x (40 mt slow x 2 sk fast)
    int hw = blockIdx.x;
    int swzid = (hw & 7) * 80 + (hw >> 3);
    int q = swzid % 80;
    int mt = q >> 1;
    int kbase = (q & 1) * (Hq / 2);
    int n0 = (swzid / 80) * 128;
    if (mt >= meta[M_NT]) return;
    int e = meta[M_TE + mt];
    int i0 = meta[M_TR + mt];
    const int* perm = meta + M_PERM;
    int vend = meta[M_POFF + e] + meta[M_CNT + e];

    GEMM_SETUP()

    const short* aSrc[4];
#pragma unroll
    for (int s = 0; s < 4; ++s) {
        int row = s * 32 + w * 8 + rlo;
        aSrc[s] = Hc + (size_t)(i0 + row) * Hq + kbase + csw * 8;
    }
    const float* bSrc = W2 + ((size_t)e * Hq + kbase + kb) * Dq + n0 + n4;

    float4 rB0[8], rB1[8];
#pragma unroll
    for (int s = 0; s < 4; ++s) glds16(aSrc[s], As + ldsA[s]);
#pragma unroll
    for (int r = 0; r < 8; ++r) rB0[r] = *(const float4*)(bSrc + (size_t)r * Dq);

    for (int t = 0; t < 32; t += 2) {
        STEP(rB0, rB1, 0, true, t + 1, Dq)
        STEP(rB1, rB0, 1, (t + 2) < 32, t + 2, Dq)
    }

    // epilogue: atomic accumulate valid rows (exactly 2 addends/elem -> bit-deterministic)
#pragma unroll
    for (int fm = 0; fm < 4; ++fm) {
        int rbase = i0 + wm + fm * 16 + fg * 4;
#pragma unroll
        for (int p = 0; p < 4; ++p) {
            int i = rbase + p;
            if (i < vend) {
                int tok = perm[i];
#pragma unroll
                for (int fn = 0; fn < 4; ++fn) {
                    int col = n0 + wn + fn * 16 + fr;
                    atomicAdd(&out[(size_t)tok * Dq + col], acc[fm][fn][p]);
                }
            }
        }
    }
}

extern "C" void kernel_launch(void* const* d_in, const int* in_sizes, int n_in,
                              void* d_out, int out_size, void* d_ws, size_t ws_size,
                              hipStream_t stream) {
    const float* x  = (const float*)d_in[0];
    const float* W1 = (const float*)d_in[1];
    const float* W2 = (const float*)d_in[2];
    const float* Wg = (const float*)d_in[3];
    const float* bg = (const float*)d_in[4];
    float* out = (float*)d_out;
    int* meta = (int*)d_ws;
    short* xb = (short*)((char*)d_ws + XB_OFF);
    short* Hc = (short*)((char*)d_ws + HC_OFF);

    k_init<<<38, 256, 0, stream>>>(meta);
    hipMemsetAsync(d_out, 0, (size_t)Tq * Dq * 4, stream);
    k_route<<<Tq / 4, 256, 0, stream>>>(x, Wg, bg, meta, xb);
    k_scan<<<1, 64, 0, stream>>>(meta);
    k_scatter<<<Tq / 256, 256, 0, stream>>>(meta);
    k_gemm1<<<1280, 256, 0, stream>>>(xb, W1, meta, Hc);
    k_gemm2<<<640, 256, 0, stream>>>(Hc, W2, meta, out);
}